// Round 13
// baseline (176.476 us; speedup 1.0000x reference)
//
#include <hip/hip_runtime.h>

typedef float f2 __attribute__((ext_vector_type(2)));

#define HW 64
#define XR (66*64)       // staging region: 66 rows x 64 cols (rows 0,65 = zero pad)
#define LH 150
#define LQ 10

// Full-wave lane shifts; bound_ctrl zero-fill == SAME padding at cols 0/63.
__device__ __forceinline__ float dpp_wshr1(float x) {   // lane i <- lane i-1
    return __builtin_bit_cast(float, __builtin_amdgcn_update_dpp(
        0, __builtin_bit_cast(int, x), 0x138, 0xF, 0xF, true));
}
__device__ __forceinline__ float dpp_wshl1(float x) {   // lane i <- lane i+1
    return __builtin_bit_cast(float, __builtin_amdgcn_update_dpp(
        0, __builtin_bit_cast(int, x), 0x130, 0xF, 0xF, true));
}
__device__ __forceinline__ f2 dpp2_shr(f2 v) { return (f2){dpp_wshr1(v.x), dpp_wshr1(v.y)}; }
__device__ __forceinline__ f2 dpp2_shl(f2 v) { return (f2){dpp_wshl1(v.x), dpp_wshl1(v.y)}; }

// VOP3P packed fp32 FMA, weight broadcast from one word of a pair.
// NOTE (R12): v_pk_fma_f32 is HALF-RATE on gfx950 (fp32 peak has no packed
// doubling) — kept because it forces VGPR residency and halves issue slots.
__device__ __forceinline__ f2 pk_fma_b0(f2 a, f2 wpair, f2 c) {
    f2 d;
    asm("v_pk_fma_f32 %0, %1, %2, %3 op_sel_hi:[1,0,1]"
        : "=v"(d) : "v"(a), "v"(wpair), "v"(c));
    return d;
}
__device__ __forceinline__ f2 pk_fma_b1(f2 a, f2 wpair, f2 c) {
    f2 d;
    asm("v_pk_fma_f32 %0, %1, %2, %3 op_sel:[0,1,0]"
        : "=v"(d) : "v"(a), "v"(wpair), "v"(c));
    return d;
}

// Per-pair conv body: taps dy=0 -> Pj (rows 2j-1,2j), dy=1 -> Oj (rows 2j,2j+1),
// dy=2 -> Pj1 (rows 2j+1,2j+2); columns L/C/R via DPP-shifted copies.
#define PAIR_BODY(acc, a, PLj, Pj, PRj, OLj, Oj, ORj, PLj1, Pj1, PRj1)   \
    acc = pk_fma_b0(PLj,  wv2[a][0], acc);                               \
    acc = pk_fma_b1(Pj,   wv2[a][0], acc);                               \
    acc = pk_fma_b0(PRj,  wv2[a][1], acc);                               \
    acc = pk_fma_b1(OLj,  wv2[a][1], acc);                               \
    acc = pk_fma_b0(Oj,   wv2[a][2], acc);                               \
    acc = pk_fma_b1(ORj,  wv2[a][2], acc);                               \
    acc = pk_fma_b0(PLj1, wv2[a][3], acc);                               \
    acc = pk_fma_b1(Pj1,  wv2[a][3], acc);                               \
    acc = pk_fma_b0(PRj1, wv2[a][4], acc);

// One block per image, 512 threads = 8 waves. lane l = column l; wave w owns
// rows 8w..8w+7 in registers (f2 row-pairs). Horizontal halos via wave DPP;
// vertical halos via 2 ds_write_b32 + 2 ds_read_b32 per lane per iter.
// The per-iter barrier is software-pipelined: halo-free row-pairs 1,2 (50% of
// FMAs) execute BEFORE __syncthreads, hiding barrier skew + halo latency.
__global__ __launch_bounds__(512, 2)
void vin_main(const float* __restrict__ X,
              const float* __restrict__ h_w,
              const float* __restrict__ h_b,
              const float* __restrict__ r_w,
              const float* __restrict__ q_w,
              const float* __restrict__ wgt,
              const int* __restrict__ kptr,
              float* __restrict__ out) {
    __shared__ float smem[3*XR + 32];      // X0 | X1 | r | weff stash (32)
    float* sR  = smem + 2*XR;
    float* sWE = smem + 3*XR;
    float* sHB = smem;                     // [2][9][64] bottom-row slots (pad [p][0]=0)
    float* sHT = smem + 1152;              // [2][9][64] top-row slots   (pad [p][8]=0)

    const int b = blockIdx.x, tid = threadIdx.x;
    const int w = tid >> 6, l = tid & 63;

    for (int i = tid; i < 3*XR + 32; i += 512) smem[i] = 0.f;
    __syncthreads();

    // ---- fused weff: wave w computes outputs j = w, w+8, w+16 (j<19) ----
    #pragma unroll
    for (int i = 0; i < 3; ++i) {
        int j = w + 8*i;
        if (j < 19) {
            float s = 0.f;
            #pragma unroll
            for (int u = 0; u < 3; ++u) {
                int t = l + 64*u;
                if (t < LH) {
                    float src = (j < 18) ? h_w[t*18 + j] : h_b[t];
                    s = fmaf(r_w[t], src, s);
                }
            }
            #pragma unroll
            for (int off = 32; off >= 1; off >>= 1)
                s += __shfl_xor(s, off);
            if (l == 0) sWE[j] = s;
        }
    }

    // ---- stage X (both channels), image rows 0..63 -> LDS rows 1..64 ----
    const float* Xb = X + (size_t)b * 2 * HW * HW;
    for (int i = tid; i < 2*64*16; i += 512) {
        int ch = i >> 10, j = i & 1023, row = j >> 4, c = j & 15;
        float4 v = *(const float4*)(Xb + ((size_t)ch*HW + row)*HW + c*4);
        *(float4*)(smem + ch*XR + (row+1)*64 + c*4) = v;
    }
    __syncthreads();

    // ---- r = conv3x3(X, weff) + beff, column mapping ----
    float wE[19];
    #pragma unroll
    for (int i = 0; i < 19; ++i) wE[i] = sWE[i];
    float rloc[8];
    {
        float xc[2][10], xl[2][10], xr[2][10];
        #pragma unroll
        for (int ch = 0; ch < 2; ++ch)
            #pragma unroll
            for (int k = 0; k < 10; ++k) {
                xc[ch][k] = smem[ch*XR + (8*w + k)*64 + l];   // global row 8w-1+k
                xl[ch][k] = dpp_wshr1(xc[ch][k]);
                xr[ch][k] = dpp_wshl1(xc[ch][k]);
            }
        #pragma unroll
        for (int i = 0; i < 8; ++i) {
            float acc = wE[18];
            #pragma unroll
            for (int ch = 0; ch < 2; ++ch)
                #pragma unroll
                for (int dy = 0; dy < 3; ++dy) {
                    acc = fmaf(xl[ch][i+dy], wE[ch*9 + dy*3 + 0], acc);
                    acc = fmaf(xc[ch][i+dy], wE[ch*9 + dy*3 + 1], acc);
                    acc = fmaf(xr[ch][i+dy], wE[ch*9 + dy*3 + 2], acc);
                }
            rloc[i] = acc;
        }
    }
    #pragma unroll
    for (int i = 0; i < 8; ++i) sR[(8*w + i + 1)*64 + l] = rloc[i];
    __syncthreads();   // X regions dead after this -> halo slots may alias

    // ---- qr[a] = conv3x3(r, q_w[a]); v0 = max_a qr ----
    f2 qr[LQ][4];
    f2 vc[4];
    {
        float rc[10], rl[10], rr2[10];
        #pragma unroll
        for (int k = 0; k < 10; ++k) {
            rc[k]  = sR[(8*w + k)*64 + l];
            rl[k]  = dpp_wshr1(rc[k]);
            rr2[k] = dpp_wshl1(rc[k]);
        }
        float vcur[8];
        #pragma unroll
        for (int a = 0; a < LQ; ++a) {
            float qa[9];
            #pragma unroll
            for (int i = 0; i < 9; ++i) qa[i] = q_w[a*9 + i];
            float acc[8];
            #pragma unroll
            for (int i = 0; i < 8; ++i) {
                float s = 0.f;
                #pragma unroll
                for (int dy = 0; dy < 3; ++dy) {
                    s = fmaf(rl[i+dy],  qa[dy*3 + 0], s);
                    s = fmaf(rc[i+dy],  qa[dy*3 + 1], s);
                    s = fmaf(rr2[i+dy], qa[dy*3 + 2], s);
                }
                acc[i] = s;
                vcur[i] = a ? fmaxf(vcur[i], s) : s;
            }
            #pragma unroll
            for (int j = 0; j < 4; ++j) qr[a][j] = (f2){acc[2*j], acc[2*j+1]};
        }
        #pragma unroll
        for (int j = 0; j < 4; ++j) vc[j] = (f2){vcur[2*j], vcur[2*j+1]};
    }
    // zero the 4 halo pad rows (alias region; X dead since last barrier)
    if (tid < 256) {
        int p = tid >> 7, half = (tid >> 6) & 1, ll = tid & 63;
        if (half == 0) sHB[p*576 + 0*64 + ll] = 0.f;
        else           sHT[p*576 + 8*64 + ll] = 0.f;
    }

    // ---- weights as 45 packed pairs ----
    f2 wv2[LQ][5];
    #pragma unroll
    for (int a = 0; a < LQ; ++a) {
        #pragma unroll
        for (int p = 0; p < 4; ++p)
            wv2[a][p] = (f2){wgt[a*9 + 2*p], wgt[a*9 + 2*p + 1]};
        wv2[a][4] = (f2){wgt[a*9 + 8], 0.f};
    }

    // ---- value iteration: v <- max_a (qr[a] + conv3x3(v, w[a])) ----
    const int km1 = kptr[0] - 1;
    const int wrB = (w+1)*64 + l;   // my bottom-row slot / partner's top-halo index
    const int wrT = w*64 + l;
    for (int t = 0; t < km1; ++t) {
        const int p = (t & 1) * 576;
        sHB[p + wrB] = vc[3].y;     // my row 8w+7
        sHT[p + wrT] = vc[0].x;     // my row 8w

        // ===== pre-barrier: halo-free pairs 1,2 (50% of FMA work) =====
        f2 P1 = (f2){vc[0].y, vc[1].x};
        f2 P2 = (f2){vc[1].y, vc[2].x};
        f2 P3 = (f2){vc[2].y, vc[3].x};
        f2 PL1 = dpp2_shr(P1), PR1 = dpp2_shl(P1);
        f2 PL2 = dpp2_shr(P2), PR2 = dpp2_shl(P2);
        f2 PL3 = dpp2_shr(P3), PR3 = dpp2_shl(P3);
        f2 OL1 = dpp2_shr(vc[1]), OR1 = dpp2_shl(vc[1]);
        f2 OL2 = dpp2_shr(vc[2]), OR2 = dpp2_shl(vc[2]);
        f2 vn1, vn2;
        #pragma unroll
        for (int a = 0; a < LQ; ++a) {
            f2 a1 = qr[a][1];
            PAIR_BODY(a1, a, PL1, P1, PR1, OL1, vc[1], OR1, PL2, P2, PR2);
            vn1 = (a == 0) ? a1 : __builtin_elementwise_max(vn1, a1);
            f2 a2 = qr[a][2];
            PAIR_BODY(a2, a, PL2, P2, PR2, OL2, vc[2], OR2, PL3, P3, PR3);
            vn2 = (a == 0) ? a2 : __builtin_elementwise_max(vn2, a2);
        }

        __syncthreads();

        // ===== post-barrier: halo pairs 0,3 =====
        float ht = sHB[p + wrT];    // row 8w-1 (zero for w==0)
        float hb = sHT[p + wrB];    // row 8w+8 (zero for w==7)
        f2 P0 = (f2){ht,       vc[0].x};
        f2 P4 = (f2){vc[3].y,  hb};
        f2 PL0 = dpp2_shr(P0), PR0 = dpp2_shl(P0);
        f2 PL4 = dpp2_shr(P4), PR4 = dpp2_shl(P4);
        f2 OL0 = dpp2_shr(vc[0]), OR0 = dpp2_shl(vc[0]);
        f2 OL3 = dpp2_shr(vc[3]), OR3 = dpp2_shl(vc[3]);
        f2 vn0, vn3;
        #pragma unroll
        for (int a = 0; a < LQ; ++a) {
            f2 a0 = qr[a][0];
            PAIR_BODY(a0, a, PL0, P0, PR0, OL0, vc[0], OR0, PL1, P1, PR1);
            vn0 = (a == 0) ? a0 : __builtin_elementwise_max(vn0, a0);
            f2 a3 = qr[a][3];
            PAIR_BODY(a3, a, PL3, P3, PR3, OL3, vc[3], OR3, PL4, P4, PR4);
            vn3 = (a == 0) ? a3 : __builtin_elementwise_max(vn3, a3);
        }
        vc[0] = vn0; vc[1] = vn1; vc[2] = vn2; vc[3] = vn3;
    }

    // ---- write out: lane l -> column l, rows 8w..8w+7 (coalesced per wave) ----
    float* ob = out + (size_t)b*HW*HW + (size_t)(8*w)*HW + l;
    #pragma unroll
    for (int j = 0; j < 4; ++j) {
        ob[(2*j)*HW]   = vc[j].x;
        ob[(2*j+1)*HW] = vc[j].y;
    }
}

extern "C" void kernel_launch(void* const* d_in, const int* in_sizes, int n_in,
                              void* d_out, int out_size, void* d_ws, size_t ws_size,
                              hipStream_t stream) {
    const float* X   = (const float*)d_in[0];
    const float* h_w = (const float*)d_in[1];
    const float* h_b = (const float*)d_in[2];
    const float* r_w = (const float*)d_in[3];
    const float* q_w = (const float*)d_in[4];
    const float* w   = (const float*)d_in[5];
    const int*   k   = (const int*)d_in[6];
    float* out = (float*)d_out;

    vin_main<<<128, 512, 0, stream>>>(X, h_w, h_b, r_w, q_w, w, k, out);
}

// Round 14
// 153.647 us; speedup vs baseline: 1.1486x; 1.1486x over previous
//
#include <hip/hip_runtime.h>

typedef float f2 __attribute__((ext_vector_type(2)));

#define HW 64
#define XR (66*64)       // staging region: 66 rows x 64 cols (rows 0,65 = zero pad)
#define LH 150
#define LQ 10

// Full-wave lane shifts; bound_ctrl zero-fill == SAME padding at cols 0/63.
__device__ __forceinline__ float dpp_wshr1(float x) {   // lane i <- lane i-1
    return __builtin_bit_cast(float, __builtin_amdgcn_update_dpp(
        0, __builtin_bit_cast(int, x), 0x138, 0xF, 0xF, true));
}
__device__ __forceinline__ float dpp_wshl1(float x) {   // lane i <- lane i+1
    return __builtin_bit_cast(float, __builtin_amdgcn_update_dpp(
        0, __builtin_bit_cast(int, x), 0x130, 0xF, 0xF, true));
}
__device__ __forceinline__ f2 dpp2_shr(f2 v) { return (f2){dpp_wshr1(v.x), dpp_wshr1(v.y)}; }
__device__ __forceinline__ f2 dpp2_shl(f2 v) { return (f2){dpp_wshl1(v.x), dpp_wshl1(v.y)}; }

// VOP3P packed fp32 FMA, weight broadcast from one word of an SGPR pair.
// Weights are wave-uniform -> "s" constraint keeps them in SGPRs (VOP3P allows
// one SGPR source); the old "v" constraint forced a v_mov s->v copy per use
// and ~100 VGPRs of pressure (R13 spilled to scratch; R10-12 AGPR churn).
__device__ __forceinline__ f2 pk_fma_b0(f2 a, f2 wpair, f2 c) {
    f2 d;
    asm("v_pk_fma_f32 %0, %1, %2, %3 op_sel_hi:[1,0,1]"
        : "=v"(d) : "v"(a), "s"(wpair), "v"(c));
    return d;
}
__device__ __forceinline__ f2 pk_fma_b1(f2 a, f2 wpair, f2 c) {
    f2 d;
    asm("v_pk_fma_f32 %0, %1, %2, %3 op_sel:[0,1,0]"
        : "=v"(d) : "v"(a), "s"(wpair), "v"(c));
    return d;
}

// One block per image, 512 threads = 8 waves. lane l = column l; wave w owns
// rows 8w..8w+7 in registers (f2 row-pairs). Horizontal halos via wave DPP;
// vertical halos via 2 ds_write_b32 + 2 ds_read_b32 per lane per iter.
__global__ __launch_bounds__(512, 2)
void vin_main(const float* __restrict__ X,
              const float* __restrict__ h_w,
              const float* __restrict__ h_b,
              const float* __restrict__ r_w,
              const float* __restrict__ q_w,
              const float* __restrict__ wgt,
              const int* __restrict__ kptr,
              float* __restrict__ out) {
    __shared__ float smem[3*XR + 32];      // X0 | X1 | r | weff stash (32)
    float* sR  = smem + 2*XR;
    float* sWE = smem + 3*XR;
    float* sHB = smem;                     // [2][9][64] bottom-row slots (pad [p][0]=0)
    float* sHT = smem + 1152;              // [2][9][64] top-row slots   (pad [p][8]=0)

    const int b = blockIdx.x, tid = threadIdx.x;
    const int w = tid >> 6, l = tid & 63;

    for (int i = tid; i < 3*XR + 32; i += 512) smem[i] = 0.f;
    __syncthreads();

    // ---- fused weff: wave w computes outputs j = w, w+8, w+16 (j<19) ----
    #pragma unroll
    for (int i = 0; i < 3; ++i) {
        int j = w + 8*i;
        if (j < 19) {
            float s = 0.f;
            #pragma unroll
            for (int u = 0; u < 3; ++u) {
                int t = l + 64*u;
                if (t < LH) {
                    float src = (j < 18) ? h_w[t*18 + j] : h_b[t];
                    s = fmaf(r_w[t], src, s);
                }
            }
            #pragma unroll
            for (int off = 32; off >= 1; off >>= 1)
                s += __shfl_xor(s, off);
            if (l == 0) sWE[j] = s;
        }
    }

    // ---- stage X (both channels), image rows 0..63 -> LDS rows 1..64 ----
    const float* Xb = X + (size_t)b * 2 * HW * HW;
    for (int i = tid; i < 2*64*16; i += 512) {
        int ch = i >> 10, j = i & 1023, row = j >> 4, c = j & 15;
        float4 v = *(const float4*)(Xb + ((size_t)ch*HW + row)*HW + c*4);
        *(float4*)(smem + ch*XR + (row+1)*64 + c*4) = v;
    }
    __syncthreads();

    // ---- r = conv3x3(X, weff) + beff, column mapping ----
    float wE[19];
    #pragma unroll
    for (int i = 0; i < 19; ++i) wE[i] = sWE[i];
    float rloc[8];
    {
        float xc[2][10], xl[2][10], xr[2][10];
        #pragma unroll
        for (int ch = 0; ch < 2; ++ch)
            #pragma unroll
            for (int k = 0; k < 10; ++k) {
                xc[ch][k] = smem[ch*XR + (8*w + k)*64 + l];   // global row 8w-1+k
                xl[ch][k] = dpp_wshr1(xc[ch][k]);
                xr[ch][k] = dpp_wshl1(xc[ch][k]);
            }
        #pragma unroll
        for (int i = 0; i < 8; ++i) {
            float acc = wE[18];
            #pragma unroll
            for (int ch = 0; ch < 2; ++ch)
                #pragma unroll
                for (int dy = 0; dy < 3; ++dy) {
                    acc = fmaf(xl[ch][i+dy], wE[ch*9 + dy*3 + 0], acc);
                    acc = fmaf(xc[ch][i+dy], wE[ch*9 + dy*3 + 1], acc);
                    acc = fmaf(xr[ch][i+dy], wE[ch*9 + dy*3 + 2], acc);
                }
            rloc[i] = acc;
        }
    }
    #pragma unroll
    for (int i = 0; i < 8; ++i) sR[(8*w + i + 1)*64 + l] = rloc[i];
    __syncthreads();   // X regions dead after this -> halo slots may alias

    // ---- qr[a] = conv3x3(r, q_w[a]); v0 = max_a qr ----
    f2 qr[LQ][4];
    f2 vc[4];
    {
        float rc[10], rl[10], rr2[10];
        #pragma unroll
        for (int k = 0; k < 10; ++k) {
            rc[k]  = sR[(8*w + k)*64 + l];
            rl[k]  = dpp_wshr1(rc[k]);
            rr2[k] = dpp_wshl1(rc[k]);
        }
        float vcur[8];
        #pragma unroll
        for (int a = 0; a < LQ; ++a) {
            float qa[9];
            #pragma unroll
            for (int i = 0; i < 9; ++i) qa[i] = q_w[a*9 + i];
            float acc[8];
            #pragma unroll
            for (int i = 0; i < 8; ++i) {
                float s = 0.f;
                #pragma unroll
                for (int dy = 0; dy < 3; ++dy) {
                    s = fmaf(rl[i+dy],  qa[dy*3 + 0], s);
                    s = fmaf(rc[i+dy],  qa[dy*3 + 1], s);
                    s = fmaf(rr2[i+dy], qa[dy*3 + 2], s);
                }
                acc[i] = s;
                vcur[i] = a ? fmaxf(vcur[i], s) : s;
            }
            #pragma unroll
            for (int j = 0; j < 4; ++j) qr[a][j] = (f2){acc[2*j], acc[2*j+1]};
        }
        #pragma unroll
        for (int j = 0; j < 4; ++j) vc[j] = (f2){vcur[2*j], vcur[2*j+1]};
    }
    // zero the 4 halo pad rows (alias region; X dead since last barrier)
    if (tid < 256) {
        int p = tid >> 7, half = (tid >> 6) & 1, ll = tid & 63;
        if (half == 0) sHB[p*576 + 0*64 + ll] = 0.f;
        else           sHT[p*576 + 8*64 + ll] = 0.f;
    }

    // ---- weights as 45 packed pairs (wave-uniform -> SGPRs) ----
    f2 wv2[LQ][5];
    #pragma unroll
    for (int a = 0; a < LQ; ++a) {
        #pragma unroll
        for (int p = 0; p < 4; ++p)
            wv2[a][p] = (f2){wgt[a*9 + 2*p], wgt[a*9 + 2*p + 1]};
        wv2[a][4] = (f2){wgt[a*9 + 8], 0.f};
    }

    // ---- value iteration: v <- max_a (qr[a] + conv3x3(v, w[a])) ----
    const int km1 = kptr[0] - 1;
    const int wrB = (w+1)*64 + l;   // my bottom-row slot / partner's top-halo index
    const int wrT = w*64 + l;
    for (int t = 0; t < km1; ++t) {
        const int p = (t & 1) * 576;
        sHB[p + wrB] = vc[3].y;     // my row 8w+7
        sHT[p + wrT] = vc[0].x;     // my row 8w
        __syncthreads();
        float ht = sHB[p + wrT];    // row 8w-1 (zero for w==0)
        float hb = sHT[p + wrB];    // row 8w+8 (zero for w==7)

        // vv[0..9] = [ht, v0..v7, hb]; aligned pairs P[j]; odd pairs = vc[j]
        f2 P[5];
        P[0] = (f2){ht,       vc[0].x};
        P[1] = (f2){vc[0].y,  vc[1].x};
        P[2] = (f2){vc[1].y,  vc[2].x};
        P[3] = (f2){vc[2].y,  vc[3].x};
        P[4] = (f2){vc[3].y,  hb};
        f2 PL[5], PR[5], OL[4], OR[4];
        #pragma unroll
        for (int j = 0; j < 5; ++j) { PL[j] = dpp2_shr(P[j]); PR[j] = dpp2_shl(P[j]); }
        #pragma unroll
        for (int j = 0; j < 4; ++j) { OL[j] = dpp2_shr(vc[j]); OR[j] = dpp2_shl(vc[j]); }

        f2 vn[4];
        #pragma unroll
        for (int a = 0; a < LQ; ++a) {
            #pragma unroll
            for (int j = 0; j < 4; ++j) {
                // taps: dy=0 -> P[j], dy=1 -> vc[j] (odd), dy=2 -> P[j+1]; cols L/C/R
                f2 acc = qr[a][j];
                acc = pk_fma_b0(PL[j],   wv2[a][0], acc);  // w0
                acc = pk_fma_b1(P[j],    wv2[a][0], acc);  // w1
                acc = pk_fma_b0(PR[j],   wv2[a][1], acc);  // w2
                acc = pk_fma_b1(OL[j],   wv2[a][1], acc);  // w3
                acc = pk_fma_b0(vc[j],   wv2[a][2], acc);  // w4
                acc = pk_fma_b1(OR[j],   wv2[a][2], acc);  // w5
                acc = pk_fma_b0(PL[j+1], wv2[a][3], acc);  // w6
                acc = pk_fma_b1(P[j+1],  wv2[a][3], acc);  // w7
                acc = pk_fma_b0(PR[j+1], wv2[a][4], acc);  // w8
                vn[j] = (a == 0) ? acc : __builtin_elementwise_max(vn[j], acc);
            }
        }
        vc[0] = vn[0]; vc[1] = vn[1]; vc[2] = vn[2]; vc[3] = vn[3];
    }

    // ---- write out: lane l -> column l, rows 8w..8w+7 (coalesced per wave) ----
    float* ob = out + (size_t)b*HW*HW + (size_t)(8*w)*HW + l;
    #pragma unroll
    for (int j = 0; j < 4; ++j) {
        ob[(2*j)*HW]   = vc[j].x;
        ob[(2*j+1)*HW] = vc[j].y;
    }
}

extern "C" void kernel_launch(void* const* d_in, const int* in_sizes, int n_in,
                              void* d_out, int out_size, void* d_ws, size_t ws_size,
                              hipStream_t stream) {
    const float* X   = (const float*)d_in[0];
    const float* h_w = (const float*)d_in[1];
    const float* h_b = (const float*)d_in[2];
    const float* r_w = (const float*)d_in[3];
    const float* q_w = (const float*)d_in[4];
    const float* w   = (const float*)d_in[5];
    const int*   k   = (const int*)d_in[6];
    float* out = (float*)d_out;

    vin_main<<<128, 512, 0, stream>>>(X, h_w, h_b, r_w, q_w, w, k, out);
}

// Round 15
// 146.422 us; speedup vs baseline: 1.2053x; 1.0493x over previous
//
#include <hip/hip_runtime.h>

typedef float f2 __attribute__((ext_vector_type(2)));

#define HW 64
#define XR (66*64)       // staging region: 66 rows x 64 cols (rows 0,65 = zero pad)
#define LH 150
#define LQ 10

// Full-wave lane shifts; bound_ctrl zero-fill == SAME padding at cols 0/63.
__device__ __forceinline__ float dpp_wshr1(float x) {   // lane i <- lane i-1
    return __builtin_bit_cast(float, __builtin_amdgcn_update_dpp(
        0, __builtin_bit_cast(int, x), 0x138, 0xF, 0xF, true));
}
__device__ __forceinline__ float dpp_wshl1(float x) {   // lane i <- lane i+1
    return __builtin_bit_cast(float, __builtin_amdgcn_update_dpp(
        0, __builtin_bit_cast(int, x), 0x130, 0xF, 0xF, true));
}
__device__ __forceinline__ f2 dpp2_shr(f2 v) { return (f2){dpp_wshr1(v.x), dpp_wshr1(v.y)}; }
__device__ __forceinline__ f2 dpp2_shl(f2 v) { return (f2){dpp_wshl1(v.x), dpp_wshl1(v.y)}; }

// VOP3P packed fp32 FMA, weight broadcast from one word of an SGPR pair
// (weights wave-uniform; VOP3P allows one SGPR source — R14).
__device__ __forceinline__ f2 pk_fma_b0(f2 a, f2 wpair, f2 c) {
    f2 d;
    asm("v_pk_fma_f32 %0, %1, %2, %3 op_sel_hi:[1,0,1]"
        : "=v"(d) : "v"(a), "s"(wpair), "v"(c));
    return d;
}
__device__ __forceinline__ f2 pk_fma_b1(f2 a, f2 wpair, f2 c) {
    f2 d;
    asm("v_pk_fma_f32 %0, %1, %2, %3 op_sel:[0,1,0]"
        : "=v"(d) : "v"(a), "s"(wpair), "v"(c));
    return d;
}

// One block per image, 1024 threads = 16 waves = 4 waves/SIMD (hides barrier
// skew that stalled the 8-wave config ~27us). lane l = column l; wave w owns
// rows 4w..4w+3 in registers (2 f2 row-pairs). Horizontal halos via wave DPP;
// vertical halos via 2 ds_write_b32 + 2 ds_read_b32 per lane per iter.
// Fits 128-VGPR cap only because conv weights live in SGPRs (R14).
__global__ __launch_bounds__(1024)
void vin_main(const float* __restrict__ X,
              const float* __restrict__ h_w,
              const float* __restrict__ h_b,
              const float* __restrict__ r_w,
              const float* __restrict__ q_w,
              const float* __restrict__ wgt,
              const int* __restrict__ kptr,
              float* __restrict__ out) {
    __shared__ float smem[3*XR + 32];      // X0 | X1 | r | weff stash (32)
    float* sR  = smem + 2*XR;
    float* sWE = smem + 3*XR;
    // halo slots alias dead X region after prologue: [2][17][64] each
    float* sHB = smem;                     // bottom rows; wave w writes [p][w+1]; pad [p][0]=0
    float* sHT = smem + 2176;              // top rows; wave w writes [p][w]; pad [p][16]=0

    const int b = blockIdx.x, tid = threadIdx.x;
    const int w = tid >> 6, l = tid & 63;

    for (int i = tid; i < 3*XR + 32; i += 1024) smem[i] = 0.f;
    __syncthreads();

    // ---- fused weff: wave w computes outputs j = w, w+16 (j<19) ----
    #pragma unroll
    for (int i = 0; i < 2; ++i) {
        int j = w + 16*i;
        if (j < 19) {
            float s = 0.f;
            #pragma unroll
            for (int u = 0; u < 3; ++u) {
                int t = l + 64*u;
                if (t < LH) {
                    float src = (j < 18) ? h_w[t*18 + j] : h_b[t];
                    s = fmaf(r_w[t], src, s);
                }
            }
            #pragma unroll
            for (int off = 32; off >= 1; off >>= 1)
                s += __shfl_xor(s, off);
            if (l == 0) sWE[j] = s;
        }
    }

    // ---- stage X (both channels), image rows 0..63 -> LDS rows 1..64 ----
    const float* Xb = X + (size_t)b * 2 * HW * HW;
    for (int i = tid; i < 2*64*16; i += 1024) {
        int ch = i >> 10, j = i & 1023, row = j >> 4, c = j & 15;
        float4 v = *(const float4*)(Xb + ((size_t)ch*HW + row)*HW + c*4);
        *(float4*)(smem + ch*XR + (row+1)*64 + c*4) = v;
    }
    __syncthreads();

    // ---- r = conv3x3(X, weff) + beff, column mapping (4 owned rows) ----
    float wE[19];
    #pragma unroll
    for (int i = 0; i < 19; ++i) wE[i] = sWE[i];
    float rloc[4];
    {
        float xc[2][6], xl[2][6], xr[2][6];
        #pragma unroll
        for (int ch = 0; ch < 2; ++ch)
            #pragma unroll
            for (int k = 0; k < 6; ++k) {
                xc[ch][k] = smem[ch*XR + (4*w + k)*64 + l];   // global row 4w-1+k
                xl[ch][k] = dpp_wshr1(xc[ch][k]);
                xr[ch][k] = dpp_wshl1(xc[ch][k]);
            }
        #pragma unroll
        for (int i = 0; i < 4; ++i) {
            float acc = wE[18];
            #pragma unroll
            for (int ch = 0; ch < 2; ++ch)
                #pragma unroll
                for (int dy = 0; dy < 3; ++dy) {
                    acc = fmaf(xl[ch][i+dy], wE[ch*9 + dy*3 + 0], acc);
                    acc = fmaf(xc[ch][i+dy], wE[ch*9 + dy*3 + 1], acc);
                    acc = fmaf(xr[ch][i+dy], wE[ch*9 + dy*3 + 2], acc);
                }
            rloc[i] = acc;
        }
    }
    #pragma unroll
    for (int i = 0; i < 4; ++i) sR[(4*w + i + 1)*64 + l] = rloc[i];
    __syncthreads();   // X regions dead after this -> halo slots may alias

    // ---- qr[a] = conv3x3(r, q_w[a]); v0 = max_a qr ----
    f2 qr[LQ][2];
    f2 vc[2];
    {
        float rc[6], rl[6], rr2[6];
        #pragma unroll
        for (int k = 0; k < 6; ++k) {
            rc[k]  = sR[(4*w + k)*64 + l];
            rl[k]  = dpp_wshr1(rc[k]);
            rr2[k] = dpp_wshl1(rc[k]);
        }
        float vcur[4];
        #pragma unroll
        for (int a = 0; a < LQ; ++a) {
            float qa[9];
            #pragma unroll
            for (int i = 0; i < 9; ++i) qa[i] = q_w[a*9 + i];
            float acc[4];
            #pragma unroll
            for (int i = 0; i < 4; ++i) {
                float s = 0.f;
                #pragma unroll
                for (int dy = 0; dy < 3; ++dy) {
                    s = fmaf(rl[i+dy],  qa[dy*3 + 0], s);
                    s = fmaf(rc[i+dy],  qa[dy*3 + 1], s);
                    s = fmaf(rr2[i+dy], qa[dy*3 + 2], s);
                }
                acc[i] = s;
                vcur[i] = a ? fmaxf(vcur[i], s) : s;
            }
            qr[a][0] = (f2){acc[0], acc[1]};
            qr[a][1] = (f2){acc[2], acc[3]};
        }
        vc[0] = (f2){vcur[0], vcur[1]};
        vc[1] = (f2){vcur[2], vcur[3]};
    }
    // zero the 4 halo pad rows (alias region; X dead since last barrier)
    if (tid < 256) {
        int p = tid >> 7, half = (tid >> 6) & 1, ll = tid & 63;
        if (half == 0) sHB[p*1088 + 0*64  + ll] = 0.f;
        else           sHT[p*1088 + 16*64 + ll] = 0.f;
    }

    // ---- weights as 45 packed pairs (wave-uniform -> SGPRs) ----
    f2 wv2[LQ][5];
    #pragma unroll
    for (int a = 0; a < LQ; ++a) {
        #pragma unroll
        for (int p = 0; p < 4; ++p)
            wv2[a][p] = (f2){wgt[a*9 + 2*p], wgt[a*9 + 2*p + 1]};
        wv2[a][4] = (f2){wgt[a*9 + 8], 0.f};
    }

    // ---- value iteration: v <- max_a (qr[a] + conv3x3(v, w[a])) ----
    const int km1 = kptr[0] - 1;
    const int wrB = (w+1)*64 + l;   // my bottom-row slot / partner's top-halo index
    const int wrT = w*64 + l;
    for (int t = 0; t < km1; ++t) {
        const int p = (t & 1) * 1088;
        sHB[p + wrB] = vc[1].y;     // my row 4w+3
        sHT[p + wrT] = vc[0].x;     // my row 4w
        __syncthreads();
        float ht = sHB[p + wrT];    // row 4w-1 (zero for w==0)
        float hb = sHT[p + wrB];    // row 4w+4 (zero for w==15)

        // vv[0..5] = [ht, v0..v3, hb]; aligned pairs P[j]; odd pairs = vc[j]
        f2 P[3];
        P[0] = (f2){ht,       vc[0].x};
        P[1] = (f2){vc[0].y,  vc[1].x};
        P[2] = (f2){vc[1].y,  hb};
        f2 PL[3], PR[3], OL[2], OR[2];
        #pragma unroll
        for (int j = 0; j < 3; ++j) { PL[j] = dpp2_shr(P[j]); PR[j] = dpp2_shl(P[j]); }
        #pragma unroll
        for (int j = 0; j < 2; ++j) { OL[j] = dpp2_shr(vc[j]); OR[j] = dpp2_shl(vc[j]); }

        f2 vn[2];
        #pragma unroll
        for (int a = 0; a < LQ; ++a) {
            #pragma unroll
            for (int j = 0; j < 2; ++j) {
                // taps: dy=0 -> P[j], dy=1 -> vc[j] (odd), dy=2 -> P[j+1]; cols L/C/R
                f2 acc = qr[a][j];
                acc = pk_fma_b0(PL[j],   wv2[a][0], acc);  // w0
                acc = pk_fma_b1(P[j],    wv2[a][0], acc);  // w1
                acc = pk_fma_b0(PR[j],   wv2[a][1], acc);  // w2
                acc = pk_fma_b1(OL[j],   wv2[a][1], acc);  // w3
                acc = pk_fma_b0(vc[j],   wv2[a][2], acc);  // w4
                acc = pk_fma_b1(OR[j],   wv2[a][2], acc);  // w5
                acc = pk_fma_b0(PL[j+1], wv2[a][3], acc);  // w6
                acc = pk_fma_b1(P[j+1],  wv2[a][3], acc);  // w7
                acc = pk_fma_b0(PR[j+1], wv2[a][4], acc);  // w8
                vn[j] = (a == 0) ? acc : __builtin_elementwise_max(vn[j], acc);
            }
        }
        vc[0] = vn[0]; vc[1] = vn[1];
    }

    // ---- write out: lane l -> column l, rows 4w..4w+3 (coalesced per wave) ----
    float* ob = out + (size_t)b*HW*HW + (size_t)(4*w)*HW + l;
    ob[0*HW] = vc[0].x;
    ob[1*HW] = vc[0].y;
    ob[2*HW] = vc[1].x;
    ob[3*HW] = vc[1].y;
}

extern "C" void kernel_launch(void* const* d_in, const int* in_sizes, int n_in,
                              void* d_out, int out_size, void* d_ws, size_t ws_size,
                              hipStream_t stream) {
    const float* X   = (const float*)d_in[0];
    const float* h_w = (const float*)d_in[1];
    const float* h_b = (const float*)d_in[2];
    const float* r_w = (const float*)d_in[3];
    const float* q_w = (const float*)d_in[4];
    const float* w   = (const float*)d_in[5];
    const int*   k   = (const int*)d_in[6];
    float* out = (float*)d_out;

    vin_main<<<128, 1024, 0, stream>>>(X, h_w, h_b, r_w, q_w, w, k, out);
}